// Round 7
// baseline (158.753 us; speedup 1.0000x reference)
//
#include <hip/hip_runtime.h>
#include <hip/hip_bf16.h>
#include <stdint.h>

#define B_ 2
#define S_ 2048
#define E_ 1024
#define H_ 16
#define D_ 64
#define M_ (B_*S_)      // 4096
#define N3 (3*E_)       // 3072

typedef unsigned short u16;
typedef float f32x4 __attribute__((ext_vector_type(4)));
typedef float f32x16 __attribute__((ext_vector_type(16)));
typedef __bf16 bf16x8 __attribute__((ext_vector_type(8)));
typedef u16 u16x8 __attribute__((ext_vector_type(8)));
typedef uint32_t u32x4 __attribute__((ext_vector_type(4)));

__device__ __forceinline__ u16 f2bf(float f){
    uint32_t u = __float_as_uint(f);
    u += 0x7fffu + ((u >> 16) & 1u);
    return (u16)(u >> 16);
}
__device__ __forceinline__ float bf2f(u16 v){ return __uint_as_float((uint32_t)v << 16); }

// ---------------- elementwise cast f32 -> bf16 (vectorized) ----------------
__global__ __launch_bounds__(256) void cast_f32_bf16(const float* __restrict__ in,
                                                     u16* __restrict__ out, int n4){
    int i = blockIdx.x * 256 + threadIdx.x;
    if (i < n4){
        float4 v = ((const float4*)in)[i];
        uint2 p;
        p.x = (uint32_t)f2bf(v.x) | ((uint32_t)f2bf(v.y) << 16);
        p.y = (uint32_t)f2bf(v.z) | ((uint32_t)f2bf(v.w) << 16);
        ((uint2*)out)[i] = p;
    }
}

// ---------------- tiled transpose + cast: in[R][C] f32 -> out[C][R] bf16 ----------------
__global__ __launch_bounds__(256) void transpose_cast(const float* __restrict__ in,
                                                      u16* __restrict__ out, int R, int C){
    __shared__ float t[32][33];
    int bx = blockIdx.x, by = blockIdx.y;
    int tx = threadIdx.x, ty = threadIdx.y;
    int x = bx * 32 + tx;
    #pragma unroll
    for (int i = 0; i < 4; i++)
        t[ty + 8*i][tx] = in[(size_t)(by*32 + ty + 8*i) * C + x];
    __syncthreads();
    #pragma unroll
    for (int i = 0; i < 4; i++)
        out[(size_t)(bx*32 + ty + 8*i) * R + by*32 + tx] = f2bf(t[tx][ty + 8*i]);
}

// ---------------- bf16 MFMA GEMM: C[M][N] = A[M][K] * BT[N][K]^T + bias ----------------
template<bool OUT_BF16>
__global__ __launch_bounds__(256) void gemm_bf16(const u16* __restrict__ A,
                                                 const u16* __restrict__ BT,
                                                 const float* __restrict__ bias,
                                                 void* __restrict__ Cout,
                                                 int M, int N, int K){
    __shared__ u16 Al[128 * 64];
    __shared__ u16 Bl[128 * 64];
    int nb = N >> 7;
    int bm = blockIdx.x / nb, bn = blockIdx.x % nb;
    int row0 = bm << 7, col0 = bn << 7;
    int tid  = threadIdx.x;
    int wave = tid >> 6, lane = tid & 63;
    int wm = wave >> 1, wn = wave & 1;
    int lr = lane & 15, lk = (lane >> 4) << 3;
    int trow = tid >> 3, tcol = (tid & 7) << 3;

    f32x4 acc[4][4] = {};

    for (int k0 = 0; k0 < K; k0 += 64){
        #pragma unroll
        for (int i = 0; i < 4; i++){
            const u16* ga = A + (size_t)(row0 + i*32 + trow) * K + k0 + tcol;
            __builtin_amdgcn_global_load_lds(
                (const __attribute__((address_space(1))) void*)ga,
                (__attribute__((address_space(3))) void*)&Al[i*2048 + wave*512],
                16, 0, 0);
        }
        #pragma unroll
        for (int i = 0; i < 4; i++){
            const u16* gb = BT + (size_t)(col0 + i*32 + trow) * K + k0 + tcol;
            __builtin_amdgcn_global_load_lds(
                (const __attribute__((address_space(1))) void*)gb,
                (__attribute__((address_space(3))) void*)&Bl[i*2048 + wave*512],
                16, 0, 0);
        }
        __syncthreads();

        #pragma unroll
        for (int ks = 0; ks < 2; ks++){
            bf16x8 af[4], bfr[4];
            #pragma unroll
            for (int m = 0; m < 4; m++)
                af[m] = *(const bf16x8*)&Al[(wm*64 + m*16 + lr) * 64 + ks*32 + lk];
            #pragma unroll
            for (int n = 0; n < 4; n++)
                bfr[n] = *(const bf16x8*)&Bl[(wn*64 + n*16 + lr) * 64 + ks*32 + lk];
            #pragma unroll
            for (int m = 0; m < 4; m++)
                #pragma unroll
                for (int n = 0; n < 4; n++)
                    acc[m][n] = __builtin_amdgcn_mfma_f32_16x16x32_bf16(af[m], bfr[n], acc[m][n], 0, 0, 0);
        }
        __syncthreads();
    }

    #pragma unroll
    for (int m = 0; m < 4; m++){
        int gr = row0 + wm*64 + m*16 + ((lane >> 4) << 2);
        #pragma unroll
        for (int n = 0; n < 4; n++){
            int gc = col0 + wn*64 + n*16 + lr;
            float bv = bias[gc];
            #pragma unroll
            for (int j = 0; j < 4; j++){
                float v = acc[m][n][j] + bv;
                if (OUT_BF16) ((u16*)Cout)[(size_t)(gr + j) * N + gc] = f2bf(v);
                else          ((float*)Cout)[(size_t)(gr + j) * N + gc] = v;
            }
        }
    }
}

// ---------------- MFMA causal flash attention v5 ----------------
// 512-thr blocks, 8 waves = 4 splits x 2 wq. q-tile = 64 rows (paired p, 31-p -> uniform
// 17 iters/block). Split s owns k-tiles {s, s+4, ...} of 32 keys (strided split-K).
// S^T = mfma(K,Q): col=lane&31=q. O^T = mfma(V^T,P). 4-way LSE combine via LDS.
// LDS = 4 splits x (4KB K + 4KB V) x dbuf = 64 KB -> 2 blocks/CU, 16 waves/CU.
__global__ __launch_bounds__(512, 4) void attn_mfma5(const u16* __restrict__ qkv,
                                                     u16* __restrict__ ctx){
    __shared__ char smem[65536];
    u16* Kb = (u16*)smem;              // [split][buf][32*64]  32KB
    u16* Vb = (u16*)(smem + 32768);    // [split][buf][64d*32k swizzled]  32KB
    // post-loop overlays:
    float* Of = (float*)smem;                  // [3][64][66] f32   (50688 B)
    float* Ml = (float*)(smem + 50688);        // [3][64][2]  f32   (1536 B)
    u16*  Olp = (u16*)(smem + 52224);          // [2][32*72] bf16   (9216 B)

    int t = blockIdx.x;
    int p = t & 15;
    int h = (t >> 4) & 15;
    int b = t >> 8;

    int tid   = threadIdx.x;
    int wave  = tid >> 6, lane = tid & 63;
    int split = wave >> 1, wq = wave & 1;
    int l31   = lane & 31, hi = lane >> 5;
    int stp   = tid & 127;              // thread index within split (2 waves)
    int kp    = stp >> 3, ch = stp & 7; // V staging: k-pair, d-chunk

    const u16* base = qkv + (size_t)b * S_ * N3;
    const float QSC = 0.17328679513998633f;   // log2(e)/sqrt(64)
    const float MASKV = -30000.f;

    #pragma unroll 1
    for (int half = 0; half < 2; ++half){
        int qb  = half ? (31 - p) : p;
        int q0  = qb << 6;
        int T   = 2*qb + 2;                // 32-key tiles needed
        int nit = (2*qb + 5) >> 2;         // ceil(T/4), uniform across splits
        int qmin = q0 + wq*32;
        int qg   = qmin + l31;
        int diag = qmin >> 5;              // last tile index this wq computes

        // Q B-frag: lane holds col q, d-slice = 16s + 8*hi, pre-scaled
        bf16x8 qf[4];
        #pragma unroll
        for (int s = 0; s < 4; s++){
            u16x8 v = *(const u16x8*)(base + (size_t)qg * N3 + h*64 + 16*s + 8*hi);
            u16x8 r;
            #pragma unroll
            for (int i = 0; i < 8; i++) r[i] = f2bf(bf2f(v[i]) * QSC);
            qf[s] = __builtin_bit_cast(bf16x8, r);
        }

        f32x16 oacc[2] = {};
        float mrow = -5000.f, lrow = 0.f;
        u16x8 va, vb;

        // ---- prologue: stage tile kt=split into buf 0 ----
        if (split < T){
            int k0 = split << 5;
            #pragma unroll
            for (int c = 0; c < 2; c++){
                int row = c*16 + wq*8 + (lane >> 3);
                int chg = (lane & 7) ^ (row & 7);
                const u16* g = base + (size_t)(k0 + row) * N3 + E_ + h*64 + chg*8;
                __builtin_amdgcn_global_load_lds(
                    (const __attribute__((address_space(1))) void*)g,
                    (__attribute__((address_space(3))) void*)&Kb[split*4096 + c*1024 + wq*512], 16, 0, 0);
            }
            va = *(const u16x8*)(base + (size_t)(k0 + 2*kp)   * N3 + 2*E_ + h*64 + ch*8);
            vb = *(const u16x8*)(base + (size_t)(k0 + 2*kp+1) * N3 + 2*E_ + h*64 + ch*8);
            #pragma unroll
            for (int e = 0; e < 8; e++){
                int d = ch*8 + e;
                int cp = (kp >> 2) ^ ((d >> 1) & 3);
                uint32_t pkv = (uint32_t)va[e] | ((uint32_t)vb[e] << 16);
                *(uint32_t*)((char*)&Vb[split*4096] + d*64 + (cp << 4) + (kp & 3)*4) = pkv;
            }
        }
        __syncthreads();

        for (int it = 0; it < nit; ++it){
            int cur = it & 1, nxt = cur ^ 1;
            int kt  = it*4 + split;
            int ktn = kt + 4;
            bool pre = (ktn < T);

            if (pre){
                int kn0 = ktn << 5;
                #pragma unroll
                for (int c = 0; c < 2; c++){
                    int row = c*16 + wq*8 + (lane >> 3);
                    int chg = (lane & 7) ^ (row & 7);
                    const u16* g = base + (size_t)(kn0 + row) * N3 + E_ + h*64 + chg*8;
                    __builtin_amdgcn_global_load_lds(
                        (const __attribute__((address_space(1))) void*)g,
                        (__attribute__((address_space(3))) void*)&Kb[split*4096 + nxt*2048 + c*1024 + wq*512], 16, 0, 0);
                }
                va = *(const u16x8*)(base + (size_t)(kn0 + 2*kp)   * N3 + 2*E_ + h*64 + ch*8);
                vb = *(const u16x8*)(base + (size_t)(kn0 + 2*kp+1) * N3 + 2*E_ + h*64 + ch*8);
            }

            if (kt <= diag){
                int k0 = kt << 5;
                const char* Kl = (const char*)&Kb[split*4096 + cur*2048];
                const char* Vt = (const char*)&Vb[split*4096 + cur*2048];
                // ---- QK^T (swapped): S^T[32k x 32q] ----
                f32x16 sac = {};
                __builtin_amdgcn_s_setprio(1);
                #pragma unroll
                for (int s = 0; s < 4; s++){
                    bf16x8 kf = *(const bf16x8*)(Kl + l31*128 + (((2*s + hi) ^ (l31 & 7)) << 4));
                    sac = __builtin_amdgcn_mfma_f32_32x32x16_bf16(kf, qf[s], sac, 0, 0, 0);
                }
                __builtin_amdgcn_s_setprio(0);
                // causal mask (diagonal tile only)
                if (k0 + 31 > qmin){
                    #pragma unroll
                    for (int r = 0; r < 16; r++){
                        int kg = k0 + (r&3) + 8*(r>>2) + 4*hi;
                        if (kg > qg) sac[r] = MASKV;
                    }
                }
                // ---- row max ----
                float mt[8];
                #pragma unroll
                for (int i = 0; i < 8; i++) mt[i] = fmaxf(sac[i], sac[i+8]);
                #pragma unroll
                for (int s2 = 4; s2 >= 1; s2 >>= 1)
                    #pragma unroll
                    for (int i = 0; i < s2; i++) mt[i] = fmaxf(mt[i], mt[i+s2]);
                float tmax = fmaxf(mt[0], __shfl_xor(mt[0], 32));
                // ---- defer-max rescale (THR = 8 in log2 domain) ----
                if (tmax > mrow + 8.f){
                    float fac = exp2f(mrow - tmax);
                    mrow = tmax;
                    lrow *= fac;
                    oacc[0] *= fac;
                    oacc[1] *= fac;
                }
                // ---- P = exp2(S - m) ----
                float pv[16];
                #pragma unroll
                for (int r = 0; r < 16; r++) pv[r] = exp2f(sac[r] - mrow);
                float ss[8];
                #pragma unroll
                for (int i = 0; i < 8; i++) ss[i] = pv[i] + pv[i+8];
                #pragma unroll
                for (int s2 = 4; s2 >= 1; s2 >>= 1)
                    #pragma unroll
                    for (int i = 0; i < s2; i++) ss[i] += ss[i+s2];
                lrow += ss[0];
                // ---- pack P to bf16, swap halves ----
                uint32_t pk[8], sw[8];
                #pragma unroll
                for (int i = 0; i < 8; i++){
                    uint32_t r;
                    asm("v_cvt_pk_bf16_f32 %0, %1, %2" : "=v"(r) : "v"(pv[2*i]), "v"(pv[2*i+1]));
                    pk[i] = r;
                }
                #pragma unroll
                for (int i = 0; i < 8; i++) sw[i] = (uint32_t)__shfl_xor((int)pk[i], 32);
                // ---- PV (swapped): O^T += V^T @ P ----
                __builtin_amdgcn_s_setprio(1);
                #pragma unroll
                for (int dt = 0; dt < 2; dt++){
                    int d = dt*32 + l31;
                    int swz = (d >> 1) & 3;
                    #pragma unroll
                    for (int s = 0; s < 2; s++){
                        bf16x8 vf = *(const bf16x8*)(Vt + d*64 + (((2*s + hi) ^ swz) << 4));
                        u32x4 pw;
                        pw[0] = hi ? sw[4*s+2] : pk[4*s+0];
                        pw[1] = hi ? sw[4*s+3] : pk[4*s+1];
                        pw[2] = hi ? pk[4*s+2] : sw[4*s+0];
                        pw[3] = hi ? pk[4*s+3] : sw[4*s+1];
                        bf16x8 pfr = __builtin_bit_cast(bf16x8, pw);
                        oacc[dt] = __builtin_amdgcn_mfma_f32_32x32x16_bf16(vf, pfr, oacc[dt], 0, 0, 0);
                    }
                }
                __builtin_amdgcn_s_setprio(0);
            }

            if (pre){
                #pragma unroll
                for (int e = 0; e < 8; e++){
                    int d = ch*8 + e;
                    int cp = (kp >> 2) ^ ((d >> 1) & 3);
                    uint32_t pkv = (uint32_t)va[e] | ((uint32_t)vb[e] << 16);
                    *(uint32_t*)((char*)&Vb[split*4096 + nxt*2048] + d*64 + (cp << 4) + (kp & 3)*4) = pkv;
                }
            }
            __syncthreads();
        }

        // ---- splits 1..3 export partials (O^T f32, m, l) ----
        if (split != 0){
            float lsum = lrow + __shfl_xor(lrow, 32);
            int qi = wq*32 + l31;
            #pragma unroll
            for (int dt = 0; dt < 2; dt++)
                #pragma unroll
                for (int r = 0; r < 16; r++){
                    int d = dt*32 + (r&3) + 8*(r>>2) + 4*hi;
                    Of[(split-1)*4224 + qi*66 + d] = oacc[dt][r];
                }
            if (hi == 0){
                Ml[(split-1)*128 + qi*2 + 0] = mrow;
                Ml[(split-1)*128 + qi*2 + 1] = lsum;
            }
        }
        __syncthreads();

        // ---- split 0 merges (4-way LSE), normalizes, transposes, stores ----
        if (split == 0){
            int qi = wq*32 + l31;
            float l0 = lrow + __shfl_xor(lrow, 32);
            float m1 = Ml[0*128 + qi*2], l1 = Ml[0*128 + qi*2 + 1];
            float m2 = Ml[1*128 + qi*2], l2 = Ml[1*128 + qi*2 + 1];
            float m3 = Ml[2*128 + qi*2], l3 = Ml[2*128 + qi*2 + 1];
            float ms = fmaxf(fmaxf(mrow, m1), fmaxf(m2, m3));
            float f0 = exp2f(mrow - ms), f1 = exp2f(m1 - ms);
            float f2 = exp2f(m2 - ms),  f3 = exp2f(m3 - ms);
            float inv = 1.0f / (l0*f0 + l1*f1 + l2*f2 + l3*f3);
            #pragma unroll
            for (int dt = 0; dt < 2; dt++)
                #pragma unroll
                for (int r = 0; r < 16; r++){
                    int d = dt*32 + (r&3) + 8*(r>>2) + 4*hi;
                    float o = oacc[dt][r]*f0 + Of[0*4224 + qi*66 + d]*f1
                            + Of[1*4224 + qi*66 + d]*f2 + Of[2*4224 + qi*66 + d]*f3;
                    Olp[wq*2304 + l31*72 + d] = f2bf(o * inv);
                }
            int q = lane >> 1, halfc = lane & 1;
            const u16* src = &Olp[wq*2304 + q*72 + halfc*32];
            u16* dst = ctx + (size_t)(b*S_ + q0 + wq*32 + q) * E_ + h*64 + halfc*32;
            #pragma unroll
            for (int i = 0; i < 4; i++)
                *(u16x8*)(dst + i*8) = *(const u16x8*)(src + i*8);
        }
        __syncthreads();   // protect overlays before next half's staging
    }
}

// ---------------- launch ----------------
extern "C" void kernel_launch(void* const* d_in, const int* in_sizes, int n_in,
                              void* d_out, int out_size, void* d_ws, size_t ws_size,
                              hipStream_t stream){
    const float* x      = (const float*)d_in[0];
    const float* w_attn = (const float*)d_in[1];
    const float* b_attn = (const float*)d_in[2];
    const float* w_proj = (const float*)d_in[3];
    const float* b_proj = (const float*)d_in[4];
    float* out = (float*)d_out;

    char* ws = (char*)d_ws;
    u16* xb   = (u16*)(ws);                         //  8 MB  [4096][1024] bf16
    u16* waT  = (u16*)(ws + 8u*1024*1024);          //  6 MB  [3072][1024] bf16
    u16* wpT  = (u16*)(ws + 14u*1024*1024);         //  2 MB  [1024][1024] bf16
    u16* qkv  = (u16*)(ws + 16u*1024*1024);         // 24 MB  [4096][3072] bf16
    u16* ctxb = (u16*)(ws + 40u*1024*1024);         //  8 MB  [4096][1024] bf16

    cast_f32_bf16<<<(M_*E_/4 + 255)/256, 256, 0, stream>>>(x, xb, M_*E_/4);
    transpose_cast<<<dim3(N3/32, E_/32), dim3(32, 8), 0, stream>>>(w_attn, waT, E_, N3);
    transpose_cast<<<dim3(E_/32, E_/32), dim3(32, 8), 0, stream>>>(w_proj, wpT, E_, E_);
    gemm_bf16<true><<<(M_/128)*(N3/128), 256, 0, stream>>>(xb, waT, b_attn, qkv, M_, N3, E_);
    attn_mfma5<<<B_*H_*16, 512, 0, stream>>>(qkv, ctxb);
    gemm_bf16<false><<<(M_/128)*(E_/128), 256, 0, stream>>>(ctxb, wpT, b_proj, out, M_, E_, E_);
}